// Round 9
// baseline (187.823 us; speedup 1.0000x reference)
//
#include <hip/hip_runtime.h>

// BahdanauAttention_16518444220431 — diagonal-DP recurrence on MI355X (gfx950).
// R9: phase-split waves. Waves 0-1 = up chain (ot 0-3 / 4-7), waves 2-3 =
// down chain. Per ks each wave reads 2 B-chunks and feeds 8 MFMAs (4ot x 2mt)
// — block LDS-read traffic HALVED vs R7 (256->128 KB/step); A streamed from
// L2 (14 ks x 4 ot, NC=2 cached) issues ahead of dependent MFMAs. Barrier
// cadence = R7 (2/step). Final GEMM = R7 verbatim (wave->2ot, both phases).
// REGISTER LEDGER (cap 256 @ 2 waves/SIMD): acc 128 AGPR + w2c[4][2]=32 +
// w1x[4]=16 + working ~50 ≈ 226. LESSONS: launch_bounds stays (256,2) —
// tighter spills acc (R2/R3: FETCH 10->400MB). Demand >~280 spills (R5).
// FETCH_SIZE >10MB = spill tripwire.

typedef __bf16 bf16x8 __attribute__((ext_vector_type(8)));
typedef __bf16 bf16x4 __attribute__((ext_vector_type(4)));
typedef float f32x16 __attribute__((ext_vector_type(16)));

#define MFMA32(a, b, c) __builtin_amdgcn_mfma_f32_32x32x16_bf16(a, b, c, 0, 0, 0)

__device__ __forceinline__ unsigned short f2bf(float f) {
  unsigned int u = __builtin_bit_cast(unsigned int, f);
  u += 0x7fffu + ((u >> 16) & 1u);
  return (unsigned short)(u >> 16);
}

// ws layout (bf16 elements):
//   [0,65536)        W2 fragments: ((ot*16+ks)*64+lane)*8+j ; o=ot*32+(lane&31), k=ks*16+(lane>>5)*8+j
//   [65536,131072)   W4 fragments, same permutation
//   [131072,135168)  W1-extra frags: lanes<32: j<4 -> W1[o][j], j==4 -> b1[o]+b2[o], else 0
//   [135168,139264)  W3-extra frags: j==4 -> b3[o]+2*b4[o]
__global__ void prep_kernel(const float* __restrict__ W1, const float* __restrict__ b1,
                            const float* __restrict__ W2, const float* __restrict__ b2,
                            const float* __restrict__ W3, const float* __restrict__ b3,
                            const float* __restrict__ W4, const float* __restrict__ b4,
                            unsigned short* __restrict__ ws) {
  int idx = blockIdx.x * 256 + threadIdx.x;
  if (idx >= 139264) return;
  float v = 0.0f;
  if (idx < 131072) {
    const float* W = (idx < 65536) ? W2 : W4;
    int i = idx & 65535;
    int j = i & 7, f = i >> 3;
    int lane = f & 63, slot = f >> 6;
    int ks = slot & 15, ot = slot >> 4;
    int o = ot * 32 + (lane & 31);
    int k = ks * 16 + (lane >> 5) * 8 + j;
    v = W[o * 256 + k];
  } else {
    int i = idx - 131072;
    bool first = (i < 4096);
    int ii = i & 4095;
    int j = ii & 7, f = ii >> 3;
    int lane = f & 63, ot = f >> 6;
    int o = ot * 32 + (lane & 31);
    if (lane < 32) {
      if (j < 4) v = first ? W1[o * 4 + j] : W3[o * 4 + j];
      else if (j == 4) v = first ? (b1[o] + b2[o]) : (b3[o] + 2.0f * b4[o]);
    }
  }
  ws[idx] = f2bf(v);
}

#define NC 2  // W2 ks cached per ot; ks NC..15 streamed from L2 each step

__global__ __launch_bounds__(256, 2)
void chain_kernel(const float* __restrict__ x, const unsigned short* __restrict__ ws,
                  float* __restrict__ out) {
  // U[ph], chunk-major: U[ph][c*64 + r] = bf16 elems [8c..8c+7] of row r.
  __shared__ int4 U[2][32 * 64];
  __shared__ int4 xw[80];   // [x0,x1,x2,x3,1,0,0,0] bf16 chunks, rows j0-8 .. j0+71
  __shared__ int4 zc;

  const int tid = threadIdx.x;
  const int l = tid & 63;
  const int w = tid >> 6;
  const int lane31 = l & 31;
  const int khalf = l >> 5;
  const int tile = blockIdx.x;
  const int b = tile >> 5;
  const int j0 = (tile & 31) * 64;

  const int4* w2f = (const int4*)ws;
  const int4* w4f = (const int4*)(ws + 65536);
  const int4* w1xg = (const int4*)(ws + 131072);
  const int4* w3xg = (const int4*)(ws + 135168);

  if (tid == 0) zc = make_int4(0, 0, 0, 0);
  if (tid < 80) {
    int j = j0 - 8 + tid;
    int4 c = make_int4(0, 0, 0, 0);
    if (j >= 0 && j < 2048) {
      const float* xb = x + (b * 4) * 2048 + j;
      unsigned short h0 = f2bf(xb[0]);
      unsigned short h1 = f2bf(xb[2048]);
      unsigned short h2 = f2bf(xb[4096]);
      unsigned short h3 = f2bf(xb[6144]);
      c = make_int4((int)(h0 | ((unsigned int)h1 << 16)),
                    (int)(h2 | ((unsigned int)h3 << 16)),
                    0x00003f80, 0);  // chunk[4] = bf16(1.0) multiplies the bias row
    }
    xw[tid] = c;
  }

  // Chain-phase decomposition: wave -> one phase, four ot tiles.
  const int ph = w >> 1;        // 0 = up, 1 = down
  const int otg = w & 1;        // ot = otg*4 + i
  const int ob0 = otg * 4;

  bf16x8 w2c[4][NC];
  bf16x8 w1x[4];
#pragma unroll
  for (int i = 0; i < 4; ++i) {
    int ot = ob0 + i;
    w1x[i] = __builtin_bit_cast(bf16x8, w1xg[ot * 64 + l]);
#pragma unroll
    for (int ks = 0; ks < NC; ++ks)
      w2c[i][ks] = __builtin_bit_cast(bf16x8, w2f[(ot * 16 + ks) * 64 + l]);
  }
  __syncthreads();

  const int mrow0 = lane31;
  const int mrow1 = 32 + lane31;
  int4* Up = U[ph];

#pragma unroll 1
  for (int t = 1; t <= 8; ++t) {
    f32x16 acc[4][2] = {};   // [ot][mt]
    // ---- extra K=16 step: adds a[pos] + bias (zero chunk beyond seq edges) ----
#pragma unroll
    for (int mt = 0; mt < 2; ++mt) {
      int m = mt ? mrow1 : mrow0;
      int widx = (ph == 0) ? (m + t - 1) : (m + 17 - t);
      const int4* p = (l < 32) ? (xw + widx) : (&zc);
      bf16x8 bx = __builtin_bit_cast(bf16x8, *p);
#pragma unroll
      for (int i = 0; i < 4; ++i) acc[i][mt] = MFMA32(w1x[i], bx, acc[i][mt]);
    }
    // ---- main GEMM over this phase's previous state (skip at t==1) ----
    if (t > 1) {
#pragma unroll
      for (int ks = 0; ks < 16; ++ks) {
        int c0 = 2 * ks + khalf;
        bf16x8 bu0 = __builtin_bit_cast(bf16x8, Up[c0 * 64 + mrow0]);
        bf16x8 bu1 = __builtin_bit_cast(bf16x8, Up[c0 * 64 + mrow1]);
#pragma unroll
        for (int i = 0; i < 4; ++i) {
          bf16x8 af;
          if (ks < NC) af = w2c[i][ks];
          else af = __builtin_bit_cast(bf16x8, w2f[((ob0 + i) * 16 + ks) * 64 + l]);
          acc[i][0] = MFMA32(af, bu0, acc[i][0]);
          acc[i][1] = MFMA32(af, bu1, acc[i][1]);
        }
      }
    }
    __syncthreads();   // all reads of U[ph] done (phase pair co-reads)
    // ---- relu + bf16 pack + chunk-major writeback (own phase buffer) ----
#pragma unroll
    for (int i = 0; i < 4; ++i) {
      int ot = ob0 + i;
#pragma unroll
      for (int mt = 0; mt < 2; ++mt) {
        int row = mt ? mrow1 : mrow0;
#pragma unroll
        for (int q = 0; q < 4; ++q) {
          bf16x4 h;
          h.x = (__bf16)fmaxf(acc[i][mt][4 * q + 0], 0.0f);
          h.y = (__bf16)fmaxf(acc[i][mt][4 * q + 1], 0.0f);
          h.z = (__bf16)fmaxf(acc[i][mt][4 * q + 2], 0.0f);
          h.w = (__bf16)fmaxf(acc[i][mt][4 * q + 3], 0.0f);
          int idx = (ot * 4 + q) * 64 + row;
          *(uint2*)((char*)(Up + idx) + khalf * 8) = __builtin_bit_cast(uint2, h);
        }
      }
    }
    __syncthreads();   // writes visible before next step's reads
  }

  // ---- final: miu^T = relu(W3x + b3 + 2b4 + W4*U0 + W4*U1), R7 layout ----
  {
    const int ot0 = w * 2;
    f32x16 acc[2][2] = {};   // [mt][ot]
    bf16x8 w3x0 = __builtin_bit_cast(bf16x8, w3xg[ot0 * 64 + l]);
    bf16x8 w3x1 = __builtin_bit_cast(bf16x8, w3xg[(ot0 + 1) * 64 + l]);
#pragma unroll
    for (int mt = 0; mt < 2; ++mt) {
      int m = mt ? mrow1 : mrow0;
      const int4* p = (l < 32) ? (xw + m + 8) : (&zc);
      bf16x8 bx = __builtin_bit_cast(bf16x8, *p);
      acc[mt][0] = MFMA32(w3x0, bx, acc[mt][0]);
      acc[mt][1] = MFMA32(w3x1, bx, acc[mt][1]);
    }
#pragma unroll 1
    for (int ph2 = 0; ph2 < 2; ++ph2) {
      const int4* Sp = U[ph2];
#pragma unroll
      for (int ks = 0; ks < 16; ++ks) {
        int c0 = 2 * ks + khalf;
        bf16x8 bu0 = __builtin_bit_cast(bf16x8, Sp[c0 * 64 + mrow0]);
        bf16x8 bu1 = __builtin_bit_cast(bf16x8, Sp[c0 * 64 + mrow1]);
        bf16x8 af0 = __builtin_bit_cast(bf16x8, w4f[(ot0 * 16 + ks) * 64 + l]);
        bf16x8 af1 = __builtin_bit_cast(bf16x8, w4f[((ot0 + 1) * 16 + ks) * 64 + l]);
        acc[0][0] = MFMA32(af0, bu0, acc[0][0]);
        acc[0][1] = MFMA32(af1, bu0, acc[0][1]);
        acc[1][0] = MFMA32(af0, bu1, acc[1][0]);
        acc[1][1] = MFMA32(af1, bu1, acc[1][1]);
      }
    }
#pragma unroll
    for (int mt = 0; mt < 2; ++mt) {
      int m = mt ? mrow1 : mrow0;
      int pbase = (b * 2048 + j0 + m) * 256;
#pragma unroll
      for (int t2 = 0; t2 < 2; ++t2) {
#pragma unroll
        for (int q = 0; q < 4; ++q) {
          int ob = (ot0 + t2) * 32 + 8 * q + 4 * khalf;
          float4 v;
          v.x = fmaxf(acc[mt][t2][4 * q + 0], 0.0f);
          v.y = fmaxf(acc[mt][t2][4 * q + 1], 0.0f);
          v.z = fmaxf(acc[mt][t2][4 * q + 2], 0.0f);
          v.w = fmaxf(acc[mt][t2][4 * q + 3], 0.0f);
          *(float4*)(out + pbase + ob) = v;
        }
      }
    }
  }
}

extern "C" void kernel_launch(void* const* d_in, const int* in_sizes, int n_in,
                              void* d_out, int out_size, void* d_ws, size_t ws_size,
                              hipStream_t stream) {
  const float* x  = (const float*)d_in[0];
  const float* W1 = (const float*)d_in[1];
  const float* b1 = (const float*)d_in[2];
  const float* W2 = (const float*)d_in[3];
  const float* b2 = (const float*)d_in[4];
  const float* W3 = (const float*)d_in[5];
  const float* b3 = (const float*)d_in[6];
  const float* W4 = (const float*)d_in[7];
  const float* b4 = (const float*)d_in[8];
  unsigned short* ws = (unsigned short*)d_ws;

  prep_kernel<<<544, 256, 0, stream>>>(W1, b1, W2, b2, W3, b3, W4, b4, ws);
  chain_kernel<<<512, 256, 0, stream>>>(x, ws, (float*)d_out);
}

// Round 10
// 132.473 us; speedup vs baseline: 1.4178x; 1.4178x over previous
//
#include <hip/hip_runtime.h>

// BahdanauAttention_16518444220431 — diagonal-DP recurrence on MI355X (gfx950).
// R10 = R8 alternating-phase structure with the L2 A-STREAM ELIMINATED:
// NC=14 ks of W2 cached in regs (112), remaining 2 ks (4 loads) issued at
// interval TOP (~500 cyc before first use). Theory: the stable ~8us/step
// across R4-R8 was mid-loop L2-latency stalls on streamed W2 fragments
// (compiler hoists only to its 128-reg comfort, re-issues rest with short
// prefetch distance). REGISTER LEDGER (cap 256 @ 2 waves/SIMD): acc 64 AGPR
// + w2c[2][14]=112 + w1x 8 + pk 32 + afs 16 + working ~25 ≈ 251.
// LESSONS: launch_bounds stays (256,2) (tighter spills acc, R2/R3);
// 128-AGPR acc + streamed A spills (R9); FETCH>10MB = spill tripwire.

typedef __bf16 bf16x8 __attribute__((ext_vector_type(8)));
typedef __bf16 bf16x4 __attribute__((ext_vector_type(4)));
typedef float f32x16 __attribute__((ext_vector_type(16)));

#define MFMA32(a, b, c) __builtin_amdgcn_mfma_f32_32x32x16_bf16(a, b, c, 0, 0, 0)

__device__ __forceinline__ unsigned short f2bf(float f) {
  unsigned int u = __builtin_bit_cast(unsigned int, f);
  u += 0x7fffu + ((u >> 16) & 1u);
  return (unsigned short)(u >> 16);
}

// ws layout (bf16 elements):
//   [0,65536)        W2 fragments: ((ot*16+ks)*64+lane)*8+j ; o=ot*32+(lane&31), k=ks*16+(lane>>5)*8+j
//   [65536,131072)   W4 fragments, same permutation
//   [131072,135168)  W1-extra frags: lanes<32: j<4 -> W1[o][j], j==4 -> b1[o]+b2[o], else 0
//   [135168,139264)  W3-extra frags: j==4 -> b3[o]+2*b4[o]
__global__ void prep_kernel(const float* __restrict__ W1, const float* __restrict__ b1,
                            const float* __restrict__ W2, const float* __restrict__ b2,
                            const float* __restrict__ W3, const float* __restrict__ b3,
                            const float* __restrict__ W4, const float* __restrict__ b4,
                            unsigned short* __restrict__ ws) {
  int idx = blockIdx.x * 256 + threadIdx.x;
  if (idx >= 139264) return;
  float v = 0.0f;
  if (idx < 131072) {
    const float* W = (idx < 65536) ? W2 : W4;
    int i = idx & 65535;
    int j = i & 7, f = i >> 3;
    int lane = f & 63, slot = f >> 6;
    int ks = slot & 15, ot = slot >> 4;
    int o = ot * 32 + (lane & 31);
    int k = ks * 16 + (lane >> 5) * 8 + j;
    v = W[o * 256 + k];
  } else {
    int i = idx - 131072;
    bool first = (i < 4096);
    int ii = i & 4095;
    int j = ii & 7, f = ii >> 3;
    int lane = f & 63, ot = f >> 6;
    int o = ot * 32 + (lane & 31);
    if (lane < 32) {
      if (j < 4) v = first ? W1[o * 4 + j] : W3[o * 4 + j];
      else if (j == 4) v = first ? (b1[o] + b2[o]) : (b3[o] + 2.0f * b4[o]);
    }
  }
  ws[idx] = f2bf(v);
}

#define NC 14  // W2 ks cached in regs; ks 14,15 loaded at interval top

__global__ __launch_bounds__(256, 2)
void chain_kernel(const float* __restrict__ x, const unsigned short* __restrict__ ws,
                  float* __restrict__ out) {
  // U[ph], chunk-major: U[ph][c*64 + r] = bf16 elems [8c..8c+7] of row r.
  __shared__ int4 U[2][32 * 64];
  __shared__ int4 xw[80];   // [x0,x1,x2,x3,1,0,0,0] bf16 chunks, rows j0-8 .. j0+71
  __shared__ int4 zc;

  const int tid = threadIdx.x;
  const int l = tid & 63;
  const int w = tid >> 6;
  const int lane31 = l & 31;
  const int khalf = l >> 5;
  const int tile = blockIdx.x;
  const int b = tile >> 5;
  const int j0 = (tile & 31) * 64;

  const int4* w2f = (const int4*)ws;
  const int4* w4f = (const int4*)(ws + 65536);
  const int4* w1xg = (const int4*)(ws + 131072);
  const int4* w3xg = (const int4*)(ws + 135168);

  if (tid == 0) zc = make_int4(0, 0, 0, 0);
  if (tid < 80) {
    int j = j0 - 8 + tid;
    int4 c = make_int4(0, 0, 0, 0);
    if (j >= 0 && j < 2048) {
      const float* xb = x + (b * 4) * 2048 + j;
      unsigned short h0 = f2bf(xb[0]);
      unsigned short h1 = f2bf(xb[2048]);
      unsigned short h2 = f2bf(xb[4096]);
      unsigned short h3 = f2bf(xb[6144]);
      c = make_int4((int)(h0 | ((unsigned int)h1 << 16)),
                    (int)(h2 | ((unsigned int)h3 << 16)),
                    0x00003f80, 0);  // chunk[4] = bf16(1.0) multiplies the bias row
    }
    xw[tid] = c;
  }

  const int ot0 = w * 2;
  bf16x8 w2c[2][NC];
  bf16x8 w1x[2];
#pragma unroll
  for (int t2 = 0; t2 < 2; ++t2) {
    w1x[t2] = __builtin_bit_cast(bf16x8, w1xg[(ot0 + t2) * 64 + l]);
#pragma unroll
    for (int ks = 0; ks < NC; ++ks)
      w2c[t2][ks] = __builtin_bit_cast(bf16x8, w2f[((ot0 + t2) * 16 + ks) * 64 + l]);
  }
  __syncthreads();

  const int mrow0 = lane31;
  const int mrow1 = 32 + lane31;

  uint2 pk[2][2][4];   // packed prev-interval results [mt][t2][q] (32 VGPRs)

#pragma unroll 1
  for (int half = 0; half < 16; ++half) {   // half = 2*(t-1) + interval
    const int t = (half >> 1) + 1;
    const int ph = half & 1;                // GEMM phase this interval

    // ---- issue the 4 non-cached A loads FIRST (used ~500 cyc later) ----
    bf16x8 afs[2][2];
#pragma unroll
    for (int s = 0; s < 2; ++s) {
      afs[s][0] = __builtin_bit_cast(bf16x8, w2f[(ot0 * 16 + NC + s) * 64 + l]);
      afs[s][1] = __builtin_bit_cast(bf16x8, w2f[((ot0 + 1) * 16 + NC + s) * 64 + l]);
    }

    f32x16 acc[2][2] = {};                  // [mt][t2] — single phase live

    // ---- write PREVIOUS interval's packed state into the other buffer ----
    if (half > 0) {
      int4* Uw = U[ph ^ 1];
#pragma unroll
      for (int mt = 0; mt < 2; ++mt) {
        int row = mt ? mrow1 : mrow0;
#pragma unroll
        for (int t2 = 0; t2 < 2; ++t2) {
#pragma unroll
          for (int q = 0; q < 4; ++q) {
            int idx = ((ot0 + t2) * 4 + q) * 64 + row;
            *(uint2*)((char*)(Uw + idx) + khalf * 8) = pk[mt][t2][q];
          }
        }
      }
    }

    // ---- extra K=16 step: adds a[pos] + bias (zero chunk beyond seq edges) ----
#pragma unroll
    for (int mt = 0; mt < 2; ++mt) {
      int m = mt ? mrow1 : mrow0;
      int widx = (ph == 0) ? (m + t - 1) : (m + 17 - t);
      const int4* p = (l < 32) ? (xw + widx) : (&zc);
      bf16x8 bx = __builtin_bit_cast(bf16x8, *p);
      acc[mt][0] = MFMA32(w1x[0], bx, acc[mt][0]);
      acc[mt][1] = MFMA32(w1x[1], bx, acc[mt][1]);
    }

    // ---- main GEMM over this phase's previous state (skip at t==1) ----
    if (t > 1) {
      const int4* Ur = U[ph];
#pragma unroll
      for (int ks = 0; ks < 16; ++ks) {
        int c0 = 2 * ks + khalf;
        bf16x8 bu0 = __builtin_bit_cast(bf16x8, Ur[c0 * 64 + mrow0]);
        bf16x8 bu1 = __builtin_bit_cast(bf16x8, Ur[c0 * 64 + mrow1]);
        bf16x8 af0, af1;
        if (ks < NC) { af0 = w2c[0][ks]; af1 = w2c[1][ks]; }
        else         { af0 = afs[ks - NC][0]; af1 = afs[ks - NC][1]; }
        acc[0][0] = MFMA32(af0, bu0, acc[0][0]);
        acc[0][1] = MFMA32(af1, bu0, acc[0][1]);
        acc[1][0] = MFMA32(af0, bu1, acc[1][0]);
        acc[1][1] = MFMA32(af1, bu1, acc[1][1]);
      }
    }

    // ---- relu + bf16 pack into registers (written NEXT interval) ----
#pragma unroll
    for (int mt = 0; mt < 2; ++mt) {
#pragma unroll
      for (int t2 = 0; t2 < 2; ++t2) {
#pragma unroll
        for (int q = 0; q < 4; ++q) {
          bf16x4 h;
          h.x = (__bf16)fmaxf(acc[mt][t2][4 * q + 0], 0.0f);
          h.y = (__bf16)fmaxf(acc[mt][t2][4 * q + 1], 0.0f);
          h.z = (__bf16)fmaxf(acc[mt][t2][4 * q + 2], 0.0f);
          h.w = (__bf16)fmaxf(acc[mt][t2][4 * q + 3], 0.0f);
          pk[mt][t2][q] = __builtin_bit_cast(uint2, h);
        }
      }
    }
    __syncthreads();
  }

  // ---- flush last down-state (pk of half=15) -> U1, then final GEMM ----
  {
    int4* Uw = U[1];
#pragma unroll
    for (int mt = 0; mt < 2; ++mt) {
      int row = mt ? mrow1 : mrow0;
#pragma unroll
      for (int t2 = 0; t2 < 2; ++t2) {
#pragma unroll
        for (int q = 0; q < 4; ++q) {
          int idx = ((ot0 + t2) * 4 + q) * 64 + row;
          *(uint2*)((char*)(Uw + idx) + khalf * 8) = pk[mt][t2][q];
        }
      }
    }
  }
  __syncthreads();

  // ---- final: miu^T = relu(W3x + b3 + 2b4 + W4*U0 + W4*U1), in-block ----
  {
    f32x16 acc[2][2] = {};   // [mt][ot]
    bf16x8 w3x0 = __builtin_bit_cast(bf16x8, w3xg[ot0 * 64 + l]);
    bf16x8 w3x1 = __builtin_bit_cast(bf16x8, w3xg[(ot0 + 1) * 64 + l]);
#pragma unroll
    for (int mt = 0; mt < 2; ++mt) {
      int m = mt ? mrow1 : mrow0;
      const int4* p = (l < 32) ? (xw + m + 8) : (&zc);
      bf16x8 bx = __builtin_bit_cast(bf16x8, *p);
      acc[mt][0] = MFMA32(w3x0, bx, acc[mt][0]);
      acc[mt][1] = MFMA32(w3x1, bx, acc[mt][1]);
    }
#pragma unroll 1
    for (int ph = 0; ph < 2; ++ph) {
      const int4* Sp = U[ph];
#pragma unroll
      for (int ks = 0; ks < 16; ++ks) {
        int c0 = 2 * ks + khalf;
        bf16x8 bu0 = __builtin_bit_cast(bf16x8, Sp[c0 * 64 + mrow0]);
        bf16x8 bu1 = __builtin_bit_cast(bf16x8, Sp[c0 * 64 + mrow1]);
        bf16x8 af0 = __builtin_bit_cast(bf16x8, w4f[(ot0 * 16 + ks) * 64 + l]);
        bf16x8 af1 = __builtin_bit_cast(bf16x8, w4f[((ot0 + 1) * 16 + ks) * 64 + l]);
        acc[0][0] = MFMA32(af0, bu0, acc[0][0]);
        acc[0][1] = MFMA32(af1, bu0, acc[0][1]);
        acc[1][0] = MFMA32(af0, bu1, acc[1][0]);
        acc[1][1] = MFMA32(af1, bu1, acc[1][1]);
      }
    }
#pragma unroll
    for (int mt = 0; mt < 2; ++mt) {
      int m = mt ? mrow1 : mrow0;
      int pbase = (b * 2048 + j0 + m) * 256;
#pragma unroll
      for (int t2 = 0; t2 < 2; ++t2) {
#pragma unroll
        for (int q = 0; q < 4; ++q) {
          int ob = (ot0 + t2) * 32 + 8 * q + 4 * khalf;
          float4 v;
          v.x = fmaxf(acc[mt][t2][4 * q + 0], 0.0f);
          v.y = fmaxf(acc[mt][t2][4 * q + 1], 0.0f);
          v.z = fmaxf(acc[mt][t2][4 * q + 2], 0.0f);
          v.w = fmaxf(acc[mt][t2][4 * q + 3], 0.0f);
          *(float4*)(out + pbase + ob) = v;
        }
      }
    }
  }
}

extern "C" void kernel_launch(void* const* d_in, const int* in_sizes, int n_in,
                              void* d_out, int out_size, void* d_ws, size_t ws_size,
                              hipStream_t stream) {
  const float* x  = (const float*)d_in[0];
  const float* W1 = (const float*)d_in[1];
  const float* b1 = (const float*)d_in[2];
  const float* W2 = (const float*)d_in[3];
  const float* b2 = (const float*)d_in[4];
  const float* W3 = (const float*)d_in[5];
  const float* b3 = (const float*)d_in[6];
  const float* W4 = (const float*)d_in[7];
  const float* b4 = (const float*)d_in[8];
  unsigned short* ws = (unsigned short*)d_ws;

  prep_kernel<<<544, 256, 0, stream>>>(W1, b1, W2, b2, W3, b3, W4, b4, ws);
  chain_kernel<<<512, 256, 0, stream>>>(x, ws, (float*)d_out);
}